// Round 3
// baseline (1393.655 us; speedup 1.0000x reference)
//
#include <hip/hip_runtime.h>
#include <hip/hip_cooperative_groups.h>
#include <math.h>

namespace cg = cooperative_groups;

// d_out element offsets: [x_q_st | loss | indices | dc]
#define OUT_XQ   0L
#define OUT_LOSS 6291456L
#define OUT_IDX  6291457L
#define OUT_DC   6299649L

// Persistent cooperative kernel: 256 blocks x 512 threads (1 block/CU).
// Block (kg = blk>>3, bg = blk&7) owns P-panel [64 k] x [1024 b].
// Thread (kk = lane, w = wave) holds P[b = bg*1024 + w*128 + j][k = kg*64 + kk], j in [0,128) -> 128 VGPRs.
__global__ __launch_bounds__(512, 2) void k_main(
    const float* __restrict__ x, const float* __restrict__ Am, const float* __restrict__ Bm,
    float* __restrict__ out,
    float* __restrict__ emb, float* __restrict__ y, double* __restrict__ A64g,
    float* __restrict__ hf, float* __restrict__ cs_part, float* __restrict__ rs_part,
    double* __restrict__ mmpart, double* __restrict__ loss_ws)
{
    cg::grid_group grid = cg::this_grid();
    const int blk = blockIdx.x;       // 256
    const int t = threadIdx.x;        // 512
    const int kk = t & 63;            // lane
    const int w  = t >> 6;            // wave 0..7
    const int kg = blk >> 3;          // 32 k-groups of 64
    const int bg = blk & 7;           // 8 b-groups of 1024

    __shared__ __align__(16) char uni[49152];           // xs[16][768] | As[64][33]
    float (*xs)[768] = (float (*)[768])uni;
    float (*As)[33]  = (float (*)[33])uni;
    __shared__ __align__(16) char gsu[4096];            // gs f32[1024] | normred[16][32] f64
    float* gs = (float*)gsu;
    double (*normred)[32] = (double (*)[32])gsu;
    __shared__ double A64s[1024];
    __shared__ double lnr64[64];
    __shared__ float  lnrf[64];
    __shared__ double hred[8][8];
    __shared__ double mmred[8][2];
    __shared__ double lossred[8];
    __shared__ int    idxs[32];
    __shared__ double s_mid, s_inva, s_beta, s_mn;
    __shared__ float  s_betaf;

    // ---------------- Phase 0a: emb rows [blk*8, +8) (f64 chain) + h_k ----------------
    {
        int kb = blk * 8;
        double hv[8];
#pragma unroll
        for (int k2 = 0; k2 < 8; ++k2) hv[k2] = 0.0;
        for (int pass = 0; pass < 2; ++pass) {
            int d = t + pass * 512;
            if (d < 768) {
#pragma unroll
                for (int k2 = 0; k2 < 8; ++k2) {
                    int k = kb + k2;
                    double e = 0.0;
#pragma unroll
                    for (int r = 0; r < 32; ++r)
                        e += (double)Am[k * 32 + r] * (double)Bm[r * 768 + d];
                    float ef = (float)e;
                    emb[(long)k * 768 + d] = ef;
                    hv[k2] += (double)ef * (double)ef;
                }
            }
        }
#pragma unroll
        for (int k2 = 0; k2 < 8; ++k2) {
            double v = hv[k2];
#pragma unroll
            for (int off = 1; off < 64; off <<= 1) v += __shfl_xor(v, off, 64);
            if (kk == 0) hred[w][k2] = v;
        }
        __syncthreads();
        if (t < 8) {
            double s = 0.0;
#pragma unroll
            for (int ww = 0; ww < 8; ++ww) s += hred[ww][t];
            hf[kb + t] = (float)s;
        }
        __syncthreads();
    }

    // ---------------- Phase 0b: y = x @ B^T (32 b/block, two 16-b halves) + ||x_b||^2 ----------------
    {
        for (int half = 0; half < 2; ++half) {
            int bbase = blk * 32 + half * 16;
            float4* XS4 = (float4*)uni;
            const float4* XG4 = (const float4*)(x + (long)bbase * 768);
            for (int i = t; i < 16 * 192; i += 512) XS4[i] = XG4[i];
            __syncthreads();
            int b = t & 15, r = t >> 4;
            const float4* B4 = (const float4*)(Bm + r * 768);
            const float4* X4 = (const float4*)(&xs[b][0]);
            float4 a0 = make_float4(0.f, 0.f, 0.f, 0.f);
#pragma unroll 8
            for (int i = 0; i < 192; ++i) {
                float4 bb = B4[i], xx = X4[i];
                a0.x = fmaf(xx.x, bb.x, a0.x);
                a0.y = fmaf(xx.y, bb.y, a0.y);
                a0.z = fmaf(xx.z, bb.z, a0.z);
                a0.w = fmaf(xx.w, bb.w, a0.w);
            }
            y[(long)(bbase + b) * 32 + r] = (a0.x + a0.y) + (a0.z + a0.w);
            // xnorm partial over d in [r*24, r*24+24)
            const float4* XN = (const float4*)(&xs[b][r * 24]);
            double nv = 0.0;
#pragma unroll
            for (int q = 0; q < 6; ++q) {
                float4 xv = XN[q];
                nv += (double)xv.x * xv.x + (double)xv.y * xv.y
                    + (double)xv.z * xv.z + (double)xv.w * xv.w;
            }
            normred[b][r] = nv;
            __syncthreads();
            if (t < 16) {
                double s = 0.0;
#pragma unroll
                for (int r2 = 0; r2 < 32; ++r2) s += normred[t][r2];
                A64g[bbase + t] = s;
            }
            __syncthreads();
        }
    }
    grid.sync();   // S1

    // ---------------- Phase 1: P-panel into registers + global min/max partials ----------------
    float P[128];
    {
        for (int i = t; i < 2048; i += 512) As[i >> 5][i & 31] = Am[kg * 2048 + i];
        for (int i = t; i < 1024; i += 512) A64s[i] = A64g[bg * 1024 + i];
        __syncthreads();
        float ar[32];
#pragma unroll
        for (int r = 0; r < 32; ++r) ar[r] = As[kk][r];
        float hk = hf[kg * 64 + kk];
        int wb = bg * 1024 + w * 128;
        double mn = 1e300, mx = -1e300;
#pragma unroll
        for (int j = 0; j < 128; ++j) {
            const float4* yb = (const float4*)(y + (long)(wb + j) * 32);  // wave-uniform broadcast
            float dot = 0.f;
#pragma unroll
            for (int rq = 0; rq < 8; ++rq) {
                float4 yv = yb[rq];
                dot = fmaf(yv.x, ar[rq * 4 + 0], dot);
                dot = fmaf(yv.y, ar[rq * 4 + 1], dot);
                dot = fmaf(yv.z, ar[rq * 4 + 2], dot);
                dot = fmaf(yv.w, ar[rq * 4 + 3], dot);
            }
            float p = fmaf(-2.f, dot, hk);
            P[j] = p;
            double dv = A64s[w * 128 + j] + (double)p;
            mn = fmin(mn, dv); mx = fmax(mx, dv);
        }
#pragma unroll
        for (int off = 1; off < 64; off <<= 1) {
            mn = fmin(mn, __shfl_xor(mn, off, 64));
            mx = fmax(mx, __shfl_xor(mx, off, 64));
        }
        if (kk == 0) { mmred[w][0] = mn; mmred[w][1] = mx; }
        __syncthreads();
        if (t == 0) {
            double m0 = 1e300, m1 = -1e300;
#pragma unroll
            for (int ww = 0; ww < 8; ++ww) { m0 = fmin(m0, mmred[ww][0]); m1 = fmax(m1, mmred[ww][1]); }
            mmpart[blk * 2] = m0; mmpart[blk * 2 + 1] = m1;
        }
    }
    grid.sync();   // S2

    // ---------------- Phase 2: sc (redundant, bitwise-identical per block) + gamma init ----------------
    {
        if (w == 0) {
            double m0 = 1e300, m1 = -1e300;
#pragma unroll
            for (int q = 0; q < 4; ++q) {
                int p = kk * 4 + q;
                m0 = fmin(m0, mmpart[p * 2]);
                m1 = fmax(m1, mmpart[p * 2 + 1]);
            }
#pragma unroll
            for (int off = 1; off < 64; off <<= 1) {
                m0 = fmin(m0, __shfl_xor(m0, off, 64));
                m1 = fmax(m1, __shfl_xor(m1, off, 64));
            }
            if (kk == 0) {
                double mid = (m1 + m0) * 0.5;
                double ampl = m1 - mid + 1e-5;
                s_mid = mid; s_inva = 1.0 / ampl; s_mn = m0;
                s_beta = 1.0 / (0.01 * ampl);
                s_betaf = (float)(1.0 / (0.01 * ampl));
            }
        }
        __syncthreads();
        double bet = s_beta, mnv = s_mn;
        for (int i = t; i < 1024; i += 512)
            gs[i] = (float)(bet * (mnv - A64s[i]));
        __syncthreads();
    }

    // colsum: per-thread two 64-b f32 chains (same granularity as R2) -> global partials
    auto colsum = [&]() {
        float betaf = s_betaf;
        float s0 = 0.f, s1 = 0.f;
#pragma unroll
        for (int j = 0; j < 64; ++j) s0 += __expf(gs[w * 128 + j] - betaf * P[j]);
#pragma unroll
        for (int j = 0; j < 64; ++j) s1 += __expf(gs[w * 128 + 64 + j] - betaf * P[j + 64]);
        int c = (bg * 16 + w * 2) * 2048 + kg * 64 + kk;
        cs_part[c] = s0; cs_part[c + 2048] = s1;
    };
    colsum();
    grid.sync();   // S3

    // ---------------- Sinkhorn: 7 colsum / 6 rowsum, P never leaves registers ----------------
    for (int it = 0; it < 7; ++it) {
        // lnr reduce (redundant per block, fixed serial order -> bitwise identical)
        if (t < 64) {
            double s = 0.0;
#pragma unroll 8
            for (int c = 0; c < 128; ++c) s += (double)cs_part[c * 2048 + kg * 64 + t];
            double l = -log(s);
            lnr64[t] = l; lnrf[t] = (float)l;
        }
        __syncthreads();
        if (it < 6) {
            float lf = lnrf[kk], betaf = s_betaf;
            float rs0 = 0.f, rs1 = 0.f;
#pragma unroll
            for (int j = 0; j < 128; ++j) {
                float v = __expf(lf - betaf * P[j]);
#pragma unroll
                for (int off = 1; off < 64; off <<= 1) v += __shfl_xor(v, off, 64);
                if (kk == (j & 63)) { if (j < 64) rs0 = v; else rs1 = v; }
            }
            int rb = kg * 8192 + bg * 1024 + w * 128;
            rs_part[rb + kk] = rs0; rs_part[rb + 64 + kk] = rs1;
            grid.sync();
            // gamma reduce (redundant per bg, fixed order)
            for (int i = t; i < 1024; i += 512) {
                double s = 0.0;
#pragma unroll
                for (int g2 = 0; g2 < 32; ++g2) s += (double)rs_part[g2 * 8192 + bg * 1024 + i];
                gs[i] = (float)(-log(s));
            }
            __syncthreads();
            colsum();
            grid.sync();
        } else {
            // final: argmax partials + dc write straight from registers
            double lb = lnr64[kk];
            double bet = s_beta, mid = s_mid, inva = s_inva;
            double av0 = 0.0, av1 = 0.0; int ai0 = 0, ai1 = 0;
            float* dc = out + OUT_DC;
            int wbl = w * 128;
            int bglob = bg * 1024 + wbl;
#pragma unroll
            for (int j = 0; j < 128; ++j) {
                double p = (double)P[j];
                double v = lb - bet * p;
                int vi = kg * 64 + kk;
#pragma unroll
                for (int off = 1; off < 64; off <<= 1) {
                    double ov = __shfl_xor(v, off, 64);
                    int oi = __shfl_xor(vi, off, 64);
                    if (ov > v || (ov == v && oi < vi)) { v = ov; vi = oi; }
                }
                if (kk == (j & 63)) { if (j < 64) { av0 = v; ai0 = vi; } else { av1 = v; ai1 = vi; } }
                dc[(long)(bglob + j) * 2048 + kg * 64 + kk] =
                    (float)((A64s[wbl + j] + p - mid) * inva);
            }
            double* av = (double*)out;                              // x_q region scratch
            int* ai = (int*)((char*)out + 2 * 1024 * 1024);
            av[kg * 8192 + bglob + kk] = av0;       ai[kg * 8192 + bglob + kk] = ai0;
            av[kg * 8192 + bglob + 64 + kk] = av1;  ai[kg * 8192 + bglob + 64 + kk] = ai1;
            grid.sync();
        }
    }

    // ---------------- idx reduce (32 kg candidates, first-max tie-break) ----------------
    {
        const double* av = (const double*)out;
        const int* ai = (const int*)((const char*)out + 2 * 1024 * 1024);
        if (t < 32) {
            int b = blk * 32 + t;
            double best = -1e300; int bi = 1 << 30;
#pragma unroll
            for (int g2 = 0; g2 < 32; ++g2) {
                double v = av[(long)g2 * 8192 + b];
                int i2 = ai[(long)g2 * 8192 + b];
                if (v > best || (v == best && i2 < bi)) { best = v; bi = i2; }
            }
            out[OUT_IDX + b] = (float)bi;
            idxs[t] = bi;
        }
        grid.sync();   // x_q scratch dead everywhere before gather overwrites it

        // gather emb -> x_q + loss
        double lacc = 0.0;
#pragma unroll
        for (int q = 0; q < 4; ++q) {
            int bl = w * 4 + q;
            int b = blk * 32 + bl;
            int idx = idxs[bl];
            const float4* E4 = (const float4*)(emb + (long)idx * 768);
            const float4* X4 = (const float4*)(x + (long)b * 768);
            float4* O4 = (float4*)(out + OUT_XQ + (long)b * 768);
#pragma unroll
            for (int i = 0; i < 3; ++i) {
                float4 e = E4[i * 64 + kk];
                float4 xv = X4[i * 64 + kk];
                O4[i * 64 + kk] = e;
                double d0 = (double)e.x - xv.x, d1 = (double)e.y - xv.y;
                double d2 = (double)e.z - xv.z, d3 = (double)e.w - xv.w;
                lacc += d0 * d0 + d1 * d1 + d2 * d2 + d3 * d3;
            }
        }
#pragma unroll
        for (int off = 1; off < 64; off <<= 1) lacc += __shfl_xor(lacc, off, 64);
        if (kk == 0) lossred[w] = lacc;
        __syncthreads();
        if (t == 0) {
            double s = 0.0;
#pragma unroll
            for (int ww = 0; ww < 8; ++ww) s += lossred[ww];
            atomicAdd(loss_ws, s);
        }
    }
}

__global__ void k_loss(const double* __restrict__ loss_ws, float* __restrict__ out) {
    out[OUT_LOSS] = (float)(loss_ws[0] * 1.25 / (double)(8192.0 * 768.0));
}

extern "C" void kernel_launch(void* const* d_in, const int* in_sizes, int n_in,
                              void* d_out, int out_size, void* d_ws, size_t ws_size,
                              hipStream_t stream) {
    const float* x  = (const float*)d_in[0];   // [8192,768]
    const float* Am = (const float*)d_in[1];   // [2048,32]
    const float* Bm = (const float*)d_in[2];   // [32,768]
    float* out = (float*)d_out;

    char* ws = (char*)d_ws;
    float*  emb     = (float*)(ws);                 // 6,291,456 B
    float*  y       = (float*)(ws + 6291456);       // 1,048,576 B
    double* A64g    = (double*)(ws + 7340032);      // 65,536 B
    float*  hf      = (float*)(ws + 7405568);       // 8,192 B
    float*  cs_part = (float*)(ws + 7413760);       // 128*2048*4 = 1,048,576 B
    float*  rs_part = (float*)(ws + 8462336);       // 32*8192*4 = 1,048,576 B
    double* mmpart  = (double*)(ws + 9510912);      // 256*2*8 = 4,096 B
    double* loss_ws = (double*)(ws + 9515008);      // 8 B
    // total ws use ~9.52 MB

    hipMemsetAsync(loss_ws, 0, sizeof(double), stream);

    void* args[] = {(void*)&x, (void*)&Am, (void*)&Bm, (void*)&out, (void*)&emb, (void*)&y,
                    (void*)&A64g, (void*)&hf, (void*)&cs_part, (void*)&rs_part,
                    (void*)&mmpart, (void*)&loss_ws};
    hipLaunchCooperativeKernel((void*)k_main, dim3(256), dim3(512), args, 0, stream);

    k_loss<<<1, 1, 0, stream>>>(loss_ws, out);
}

// Round 4
// 552.568 us; speedup vs baseline: 2.5221x; 2.5221x over previous
//
#include <hip/hip_runtime.h>
#include <math.h>

// Problem constants
#define B_N 8192
#define K_N 2048
#define D_N 768
#define R_N 32

// d_out element offsets: [x_q_st | loss | indices | dc]
#define OUT_XQ   0L
#define OUT_LOSS 6291456L
#define OUT_IDX  6291457L
#define OUT_DC   6299649L   // odd -> dc/P rows are 4B-aligned only; k==3 (mod 4) is 16B-aligned

// ---------------- emb = A @ B (f64 accumulate), h_k = ||e_k||^2  [bitwise == R2] ----------------
__global__ __launch_bounds__(256) void k_emb(const float* __restrict__ A,
                                             const float* __restrict__ Bm,
                                             float* __restrict__ emb,
                                             float* __restrict__ hf) {
    int k = blockIdx.x, t = threadIdx.x;
    __shared__ float a_s[R_N];
    if (t < R_N) a_s[t] = A[k * R_N + t];
    __syncthreads();
    double hpart = 0.0;
    for (int d = t; d < D_N; d += 256) {
        double e = 0.0;
#pragma unroll
        for (int r = 0; r < R_N; ++r) e += (double)a_s[r] * (double)Bm[r * D_N + d];
        float ef = (float)e;
        emb[(long)k * D_N + d] = ef;
        hpart += (double)ef * (double)ef;
    }
    __shared__ double red[256];
    red[t] = hpart; __syncthreads();
    for (int s = 128; s > 0; s >>= 1) { if (t < s) red[t] += red[t + s]; __syncthreads(); }
    if (t == 0) hf[k] = (float)red[0];
}

// ---------------- A64[b] = ||x_b||^2 (f64)  [bitwise == R2] ----------------
__global__ __launch_bounds__(256) void k_xnorm(const float* __restrict__ x,
                                               double* __restrict__ A64) {
    int b = blockIdx.x, t = threadIdx.x;
    double s = 0.0;
    for (int d = t; d < D_N; d += 256) {
        double v = (double)x[(long)b * D_N + d];
        s += v * v;
    }
    __shared__ double red[256];
    red[t] = s; __syncthreads();
    for (int st = 128; st > 0; st >>= 1) { if (t < st) red[t] += red[t + st]; __syncthreads(); }
    if (t == 0) A64[b] = red[0];
}

// ---------------- y = x @ B^T : [8192, 32]  [bitwise == R2] ----------------
__global__ __launch_bounds__(256) void k_ygemm(const float* __restrict__ x,
                                               const float* __restrict__ Bm,
                                               float* __restrict__ y) {
    __shared__ float xs[16][768];
    int t = threadIdx.x;
    int b0 = blockIdx.x * 16;
    for (int row = 0; row < 16; ++row)
        for (int d = t; d < D_N; d += 256)
            xs[row][d] = x[(long)(b0 + row) * D_N + d];
    __syncthreads();
    int b = t >> 5, r = t & 31;
    const float4* B4 = (const float4*)(Bm + (long)r * D_N);
    const float4* X0 = (const float4*)(&xs[b][0]);
    const float4* X1 = (const float4*)(&xs[b + 8][0]);
    float4 a0 = make_float4(0.f, 0.f, 0.f, 0.f);
    float4 a1 = make_float4(0.f, 0.f, 0.f, 0.f);
#pragma unroll 8
    for (int i = 0; i < 192; ++i) {
        float4 bb = B4[i];
        float4 x0 = X0[i], x1 = X1[i];
        a0.x = fmaf(x0.x, bb.x, a0.x); a0.y = fmaf(x0.y, bb.y, a0.y);
        a0.z = fmaf(x0.z, bb.z, a0.z); a0.w = fmaf(x0.w, bb.w, a0.w);
        a1.x = fmaf(x1.x, bb.x, a1.x); a1.y = fmaf(x1.y, bb.y, a1.y);
        a1.z = fmaf(x1.z, bb.z, a1.z); a1.w = fmaf(x1.w, bb.w, a1.w);
    }
    y[(long)(b0 + b) * R_N + r] = (a0.x + a0.y) + (a0.z + a0.w);
    y[(long)(b0 + b + 8) * R_N + r] = (a1.x + a1.y) + (a1.z + a1.w);
}

// ---------------- P[b,k] = h_k - 2 y_b.A_k + fused min/max partials  [bitwise == R2] ----------------
__global__ __launch_bounds__(256) void k_pgemm(const float* __restrict__ Am,
                                               const float* __restrict__ y,
                                               const float* __restrict__ hf,
                                               const double* __restrict__ A64,
                                               float* __restrict__ P,
                                               double* __restrict__ mmpart) {
    __shared__ float As[256][33];
    __shared__ float ys[32][32];
    __shared__ double a64s[32];
    __shared__ double smn[256], smx[256];
    int t = threadIdx.x;
    int k0 = blockIdx.x * 256, b0 = blockIdx.y * 32;
    for (int i = t; i < 256 * 32; i += 256) As[i >> 5][i & 31] = Am[(long)(k0 + (i >> 5)) * R_N + (i & 31)];
    for (int i = t; i < 32 * 32; i += 256) ys[i >> 5][i & 31] = y[(long)(b0 + (i >> 5)) * R_N + (i & 31)];
    if (t < 32) a64s[t] = A64[b0 + t];
    __syncthreads();
    int k = k0 + t;
    float ar[32];
#pragma unroll
    for (int r = 0; r < 32; ++r) ar[r] = As[t][r];
    float hk = hf[k];
    double mn = 1e300, mx = -1e300;
#pragma unroll 4
    for (int b = 0; b < 32; ++b) {
        float dot = 0.f;
#pragma unroll
        for (int r = 0; r < 32; ++r) dot = fmaf(ys[b][r], ar[r], dot);
        float p = fmaf(-2.f, dot, hk);
        P[(long)(b0 + b) * K_N + k] = p;
        double dv = a64s[b] + (double)p;
        mn = fmin(mn, dv); mx = fmax(mx, dv);
    }
    smn[t] = mn; smx[t] = mx; __syncthreads();
    for (int s = 128; s > 0; s >>= 1) {
        if (t < s) { smn[t] = fmin(smn[t], smn[t + s]); smx[t] = fmax(smx[t], smx[t + s]); }
        __syncthreads();
    }
    if (t == 0) {
        int bid = blockIdx.y * gridDim.x + blockIdx.x;
        mmpart[2 * bid] = smn[0]; mmpart[2 * bid + 1] = smx[0];
    }
}

// ---------------- minmax reduce -> sc, fused gamma init ----------------
__global__ __launch_bounds__(256) void k_minmax2(const double* __restrict__ part,
                                                 double* __restrict__ sc,
                                                 const double* __restrict__ A64,
                                                 float* __restrict__ gammaf, int nblk) {
    int t = threadIdx.x;
    double mn = 1e300, mx = -1e300;
    for (int i = t; i < nblk; i += 256) {
        mn = fmin(mn, part[2 * i]); mx = fmax(mx, part[2 * i + 1]);
    }
    __shared__ double smn[256], smx[256];
    __shared__ double ssc[4];
    smn[t] = mn; smx[t] = mx; __syncthreads();
    for (int s = 128; s > 0; s >>= 1) {
        if (t < s) { smn[t] = fmin(smn[t], smn[t + s]); smx[t] = fmax(smx[t], smx[t + s]); }
        __syncthreads();
    }
    if (t == 0) {
        double mid = (smx[0] + smn[0]) * 0.5;
        double ampl = smx[0] - mid + 1e-5;
        sc[0] = ssc[0] = mid; sc[1] = ssc[1] = ampl; sc[2] = ssc[2] = smn[0];
        sc[3] = ssc[3] = 1.0 / (0.01 * ampl);   // beta
    }
    __syncthreads();
    double bet = ssc[3], mnv = ssc[2];
    for (int i = t; i < B_N; i += 256)
        gammaf[i] = (float)(bet * (mnv - A64[i]));
}

// ---------------- Sinkhorn half-step A: column-sum partials  [bitwise == R2] ----------------
__global__ __launch_bounds__(256) void k_colsum(const float* __restrict__ P,
                                                const float* __restrict__ gammaf,
                                                const double* __restrict__ sc,
                                                float* __restrict__ part) {
    __shared__ float gs[64];
    int t = threadIdx.x;
    int k = blockIdx.x * 256 + t;
    int b0 = blockIdx.y * 64;
    if (t < 64) gs[t] = gammaf[b0 + t];
    __syncthreads();
    float betaf = (float)sc[3];
    float s0 = 0.f, s1 = 0.f, s2 = 0.f, s3 = 0.f;
#pragma unroll
    for (int j = 0; j < 64; j += 4) {
        s0 += __expf(gs[j]     - betaf * P[(long)(b0 + j)     * K_N + k]);
        s1 += __expf(gs[j + 1] - betaf * P[(long)(b0 + j + 1) * K_N + k]);
        s2 += __expf(gs[j + 2] - betaf * P[(long)(b0 + j + 2) * K_N + k]);
        s3 += __expf(gs[j + 3] - betaf * P[(long)(b0 + j + 3) * K_N + k]);
    }
    part[(long)blockIdx.y * K_N + k] = (s0 + s1) + (s2 + s3);
}

__global__ __launch_bounds__(256) void k_colsum2(const float* __restrict__ part,
                                                 double* __restrict__ lnr64,
                                                 float* __restrict__ lnrf) {
    int k = blockIdx.x * 256 + threadIdx.x;
    double s = 0.0;
#pragma unroll 4
    for (int c = 0; c < 128; ++c) s += (double)part[(long)c * K_N + k];
    double l = -log(s);
    lnr64[k] = l; lnrf[k] = (float)l;
}

// ---------------- Sinkhorn half-step B: one wave per b-row, float4 on aligned lattice ----------------
__global__ __launch_bounds__(512) void k_rowsum(const float* __restrict__ P,
                                                const float* __restrict__ lnrf,
                                                const double* __restrict__ sc,
                                                float* __restrict__ gammaf) {
    int t = threadIdx.x, l = t & 63, w = t >> 6;
    long b = (long)blockIdx.x * 8 + w;
    const float* row = P + b * K_N;
    float betaf = (float)sc[3];
    float4 acc = make_float4(0.f, 0.f, 0.f, 0.f);
    float se = 0.f;
    if (l < 3)   se = __expf(lnrf[l] - betaf * row[l]);          // k = 0,1,2
    if (l == 63) se = __expf(lnrf[2047] - betaf * row[2047]);    // k = 2047
#pragma unroll
    for (int c = 0; c < 8; ++c) {
        int i = l + 64 * c;
        if (i < 511) {
            int k = 3 + 4 * i;                                   // 16B-aligned on the odd base
            float4 p = *(const float4*)(row + k);
            acc.x += __expf(lnrf[k]     - betaf * p.x);
            acc.y += __expf(lnrf[k + 1] - betaf * p.y);
            acc.z += __expf(lnrf[k + 2] - betaf * p.z);
            acc.w += __expf(lnrf[k + 3] - betaf * p.w);
        }
    }
    double s = ((double)acc.x + (double)acc.y) + ((double)acc.z + (double)acc.w) + (double)se;
#pragma unroll
    for (int off = 1; off < 64; off <<= 1) s += __shfl_xor(s, off, 64);
    if (l == 0) gammaf[b] = (float)(-log(s));
}

// ---------------- final: one wave per row — argmax(f64) + dc in place + gather + loss ----------------
__global__ __launch_bounds__(512) void k_final(const double* __restrict__ lnr64,
                                               const double* __restrict__ sc,
                                               const double* __restrict__ A64,
                                               const float* __restrict__ emb,
                                               const float* __restrict__ x,
                                               float* __restrict__ out,
                                               double* __restrict__ loss_ws) {
    int t = threadIdx.x, l = t & 63, w = t >> 6;
    long b = (long)blockIdx.x * 8 + w;
    float* row = out + OUT_DC + b * K_N;     // P in, dc out (disjoint per wave)
    double beta = sc[3], mid = sc[0], inva = 1.0 / sc[1];
    double a64b = A64[b];
    double best = -1e300; int bi = 1 << 30;
    if (l < 3) {                                               // k = 0,1,2 first (ascending in-lane)
        double p = (double)row[l];
        double dec = lnr64[l] - beta * p;
        if (dec > best) { best = dec; bi = l; }
        row[l] = (float)((a64b + p - mid) * inva);
    }
#pragma unroll
    for (int c = 0; c < 8; ++c) {
        int i = l + 64 * c;
        if (i < 511) {
            int k = 3 + 4 * i;
            float4 p4 = *(const float4*)(row + k);
            double p0 = p4.x, p1 = p4.y, p2 = p4.z, p3 = p4.w;
            double d0 = lnr64[k] - beta * p0;
            double d1 = lnr64[k + 1] - beta * p1;
            double d2 = lnr64[k + 2] - beta * p2;
            double d3 = lnr64[k + 3] - beta * p3;
            if (d0 > best) { best = d0; bi = k; }
            if (d1 > best) { best = d1; bi = k + 1; }
            if (d2 > best) { best = d2; bi = k + 2; }
            if (d3 > best) { best = d3; bi = k + 3; }
            float4 dcv;
            dcv.x = (float)((a64b + p0 - mid) * inva);
            dcv.y = (float)((a64b + p1 - mid) * inva);
            dcv.z = (float)((a64b + p2 - mid) * inva);
            dcv.w = (float)((a64b + p3 - mid) * inva);
            *(float4*)(row + k) = dcv;
        }
    }
    if (l == 63) {                                             // k = 2047 last (ascending in-lane)
        double p = (double)row[2047];
        double dec = lnr64[2047] - beta * p;
        if (dec > best) { best = dec; bi = 2047; }
        row[2047] = (float)((a64b + p - mid) * inva);
    }
#pragma unroll
    for (int off = 1; off < 64; off <<= 1) {                   // first-max: min idx on ties
        double ov = __shfl_xor(best, off, 64);
        int oi = __shfl_xor(bi, off, 64);
        if (ov > best || (ov == best && oi < bi)) { best = ov; bi = oi; }
    }
    if (l == 0) out[OUT_IDX + b] = (float)bi;

    const float4* E4 = (const float4*)(emb + (long)bi * D_N);
    const float4* X4 = (const float4*)(x + b * D_N);
    float4* O4 = (float4*)(out + OUT_XQ + b * D_N);
    double lacc = 0.0;
#pragma unroll
    for (int i = 0; i < 3; ++i) {
        float4 e = E4[i * 64 + l];
        float4 xv = X4[i * 64 + l];
        O4[i * 64 + l] = e;
        double d0 = (double)e.x - xv.x, d1 = (double)e.y - xv.y;
        double d2 = (double)e.z - xv.z, d3 = (double)e.w - xv.w;
        lacc += d0 * d0 + d1 * d1 + d2 * d2 + d3 * d3;
    }
#pragma unroll
    for (int off = 1; off < 64; off <<= 1) lacc += __shfl_xor(lacc, off, 64);
    if (l == 0) atomicAdd(loss_ws, lacc);
}

__global__ void k_loss(const double* __restrict__ loss_ws, float* __restrict__ out) {
    out[OUT_LOSS] = (float)(loss_ws[0] * 1.25 / (double)((long)B_N * D_N));
}

extern "C" void kernel_launch(void* const* d_in, const int* in_sizes, int n_in,
                              void* d_out, int out_size, void* d_ws, size_t ws_size,
                              hipStream_t stream) {
    const float* x  = (const float*)d_in[0];   // [8192,768]
    const float* Am = (const float*)d_in[1];   // [2048,32]
    const float* Bm = (const float*)d_in[2];   // [32,768]
    float* out = (float*)d_out;
    float* P = out + OUT_DC;                   // P lives in dc region; k_final converts in place

    char* ws = (char*)d_ws;
    float*  emb     = (float*)(ws);                 // 6,291,456 B
    float*  y       = (float*)(ws + 6291456);       // 1,048,576 B
    double* A64     = (double*)(ws + 7340032);      // 65,536 B
    float*  hf      = (float*)(ws + 7405568);       // 8,192 B
    float*  gammaf  = (float*)(ws + 7413760);       // 32,768 B
    double* lnr64   = (double*)(ws + 7446528);      // 16,384 B
    float*  lnrf    = (float*)(ws + 7462912);       // 8,192 B
    float*  cs_part = (float*)(ws + 7471104);       // 128*2048*4 = 1,048,576 B
    double* mmpart  = (double*)(ws + 8519680);      // 2048*2*8 = 32,768 B
    double* sc      = (double*)(ws + 8552448);      // 4 doubles
    double* loss_ws = (double*)(ws + 8552704);      // 1 double
    // total ws use ~8.55 MB

    hipMemsetAsync(loss_ws, 0, sizeof(double), stream);

    k_emb<<<K_N, 256, 0, stream>>>(Am, Bm, emb, hf);
    k_xnorm<<<B_N, 256, 0, stream>>>(x, A64);
    k_ygemm<<<B_N / 16, 256, 0, stream>>>(x, Bm, y);

    dim3 gp(K_N / 256, B_N / 32);
    k_pgemm<<<gp, 256, 0, stream>>>(Am, y, hf, A64, P, mmpart);
    k_minmax2<<<1, 256, 0, stream>>>(mmpart, sc, A64, gammaf, 2048);

    // Contraction per full cycle <= tanh^2(0.15) ~ 0.022; residual after 6 colsums
    // ~ 0.045 * 0.022^5 ~ 2e-10 in lnr — far below the ~1e-7 min top-2 decision gap.
    const int CS = 6;
    dim3 ga(K_N / 256, 128);
    for (int it = 0; it < CS; ++it) {
        k_colsum<<<ga, 256, 0, stream>>>(P, gammaf, sc, cs_part);
        k_colsum2<<<K_N / 256, 256, 0, stream>>>(cs_part, lnr64, lnrf);
        if (it < CS - 1)
            k_rowsum<<<B_N / 8, 512, 0, stream>>>(P, lnrf, sc, gammaf);
    }

    k_final<<<B_N / 8, 512, 0, stream>>>(lnr64, sc, A64, emb, x, out, loss_ws);
    k_loss<<<1, 1, 0, stream>>>(loss_ws, out);
}

// Round 5
// 463.857 us; speedup vs baseline: 3.0045x; 1.1912x over previous
//
#include <hip/hip_runtime.h>
#include <math.h>

// Problem constants
#define B_N 8192
#define K_N 2048
#define D_N 768
#define R_N 32

// d_out element offsets: [x_q_st | loss | indices | dc]
#define OUT_XQ   0L
#define OUT_LOSS 6291456L
#define OUT_IDX  6291457L
#define OUT_DC   6299649L   // odd -> dc/P rows are 4B-aligned only; k==3 (mod 4) is 16B-aligned

// ---------------- emb = A @ B (f64 accumulate), h_k = ||e_k||^2  [bitwise == R4] ----------------
__global__ __launch_bounds__(256) void k_emb(const float* __restrict__ A,
                                             const float* __restrict__ Bm,
                                             float* __restrict__ emb,
                                             float* __restrict__ hf) {
    int k = blockIdx.x, t = threadIdx.x;
    __shared__ float a_s[R_N];
    if (t < R_N) a_s[t] = A[k * R_N + t];
    __syncthreads();
    double hpart = 0.0;
    for (int d = t; d < D_N; d += 256) {
        double e = 0.0;
#pragma unroll
        for (int r = 0; r < R_N; ++r) e += (double)a_s[r] * (double)Bm[r * D_N + d];
        float ef = (float)e;
        emb[(long)k * D_N + d] = ef;
        hpart += (double)ef * (double)ef;
    }
    __shared__ double red[256];
    red[t] = hpart; __syncthreads();
    for (int s = 128; s > 0; s >>= 1) { if (t < s) red[t] += red[t + s]; __syncthreads(); }
    if (t == 0) hf[k] = (float)red[0];
}

// ---------------- y = x @ B^T [bitwise == R4] + fused ||x_b||^2 (f64) ----------------
__global__ __launch_bounds__(256) void k_ygemm(const float* __restrict__ x,
                                               const float* __restrict__ Bm,
                                               float* __restrict__ y,
                                               double* __restrict__ A64) {
    __shared__ float xs[16][768];
    __shared__ double normred[16][32];
    int t = threadIdx.x;
    int b0 = blockIdx.x * 16;
    for (int row = 0; row < 16; ++row)
        for (int d = t; d < D_N; d += 256)
            xs[row][d] = x[(long)(b0 + row) * D_N + d];
    __syncthreads();
    int b = t >> 5, r = t & 31;
    const float4* B4 = (const float4*)(Bm + (long)r * D_N);
    const float4* X0 = (const float4*)(&xs[b][0]);
    const float4* X1 = (const float4*)(&xs[b + 8][0]);
    float4 a0 = make_float4(0.f, 0.f, 0.f, 0.f);
    float4 a1 = make_float4(0.f, 0.f, 0.f, 0.f);
#pragma unroll 8
    for (int i = 0; i < 192; ++i) {
        float4 bb = B4[i];
        float4 x0 = X0[i], x1 = X1[i];
        a0.x = fmaf(x0.x, bb.x, a0.x); a0.y = fmaf(x0.y, bb.y, a0.y);
        a0.z = fmaf(x0.z, bb.z, a0.z); a0.w = fmaf(x0.w, bb.w, a0.w);
        a1.x = fmaf(x1.x, bb.x, a1.x); a1.y = fmaf(x1.y, bb.y, a1.y);
        a1.z = fmaf(x1.z, bb.z, a1.z); a1.w = fmaf(x1.w, bb.w, a1.w);
    }
    y[(long)(b0 + b) * R_N + r] = (a0.x + a0.y) + (a0.z + a0.w);
    y[(long)(b0 + b + 8) * R_N + r] = (a1.x + a1.y) + (a1.z + a1.w);
    // fused xnorm partials: thread (b,r) sums d = r + 32*q (conflict-free banks)
    double nv0 = 0.0, nv1 = 0.0;
#pragma unroll
    for (int q = 0; q < 24; ++q) {
        double v0 = (double)xs[b][r + 32 * q];
        double v1 = (double)xs[b + 8][r + 32 * q];
        nv0 += v0 * v0; nv1 += v1 * v1;
    }
    normred[b][r] = nv0; normred[b + 8][r] = nv1;
    __syncthreads();
    if (t < 16) {
        double s = 0.0;
#pragma unroll
        for (int r2 = 0; r2 < 32; ++r2) s += normred[t][r2];
        A64[b0 + t] = s;
    }
}

// ---------------- P[b,k] = h_k - 2 y_b.A_k + fused min/max partials  [bitwise == R4] ----------------
__global__ __launch_bounds__(256) void k_pgemm(const float* __restrict__ Am,
                                               const float* __restrict__ y,
                                               const float* __restrict__ hf,
                                               const double* __restrict__ A64,
                                               float* __restrict__ P,
                                               double* __restrict__ mmpart) {
    __shared__ float As[256][33];
    __shared__ float ys[32][32];
    __shared__ double a64s[32];
    __shared__ double smn[256], smx[256];
    int t = threadIdx.x;
    int k0 = blockIdx.x * 256, b0 = blockIdx.y * 32;
    for (int i = t; i < 256 * 32; i += 256) As[i >> 5][i & 31] = Am[(long)(k0 + (i >> 5)) * R_N + (i & 31)];
    for (int i = t; i < 32 * 32; i += 256) ys[i >> 5][i & 31] = y[(long)(b0 + (i >> 5)) * R_N + (i & 31)];
    if (t < 32) a64s[t] = A64[b0 + t];
    __syncthreads();
    int k = k0 + t;
    float ar[32];
#pragma unroll
    for (int r = 0; r < 32; ++r) ar[r] = As[t][r];
    float hk = hf[k];
    double mn = 1e300, mx = -1e300;
#pragma unroll 4
    for (int b = 0; b < 32; ++b) {
        float dot = 0.f;
#pragma unroll
        for (int r = 0; r < 32; ++r) dot = fmaf(ys[b][r], ar[r], dot);
        float p = fmaf(-2.f, dot, hk);
        P[(long)(b0 + b) * K_N + k] = p;
        double dv = a64s[b] + (double)p;
        mn = fmin(mn, dv); mx = fmax(mx, dv);
    }
    smn[t] = mn; smx[t] = mx; __syncthreads();
    for (int s = 128; s > 0; s >>= 1) {
        if (t < s) { smn[t] = fmin(smn[t], smn[t + s]); smx[t] = fmax(smx[t], smx[t + s]); }
        __syncthreads();
    }
    if (t == 0) {
        int bid = blockIdx.y * gridDim.x + blockIdx.x;
        mmpart[2 * bid] = smn[0]; mmpart[2 * bid + 1] = smx[0];
    }
}

// ---------------- minmax reduce -> sc, fused gamma init  [== R4] ----------------
__global__ __launch_bounds__(256) void k_minmax2(const double* __restrict__ part,
                                                 double* __restrict__ sc,
                                                 const double* __restrict__ A64,
                                                 float* __restrict__ gammaf, int nblk) {
    int t = threadIdx.x;
    double mn = 1e300, mx = -1e300;
    for (int i = t; i < nblk; i += 256) {
        mn = fmin(mn, part[2 * i]); mx = fmax(mx, part[2 * i + 1]);
    }
    __shared__ double smn[256], smx[256];
    __shared__ double ssc[4];
    smn[t] = mn; smx[t] = mx; __syncthreads();
    for (int s = 128; s > 0; s >>= 1) {
        if (t < s) { smn[t] = fmin(smn[t], smn[t + s]); smx[t] = fmax(smx[t], smx[t + s]); }
        __syncthreads();
    }
    if (t == 0) {
        double mid = (smx[0] + smn[0]) * 0.5;
        double ampl = smx[0] - mid + 1e-5;
        sc[0] = ssc[0] = mid; sc[1] = ssc[1] = ampl; sc[2] = ssc[2] = smn[0];
        sc[3] = ssc[3] = 1.0 / (0.01 * ampl);   // beta
    }
    __syncthreads();
    double bet = ssc[3], mnv = ssc[2];
    for (int i = t; i < B_N; i += 256)
        gammaf[i] = (float)(bet * (mnv - A64[i]));
}

// ---------------- first colsum (c0)  [bitwise == R4] ----------------
__global__ __launch_bounds__(256) void k_colsum(const float* __restrict__ P,
                                                const float* __restrict__ gammaf,
                                                const double* __restrict__ sc,
                                                float* __restrict__ part) {
    __shared__ float gs[64];
    int t = threadIdx.x;
    int k = blockIdx.x * 256 + t;
    int b0 = blockIdx.y * 64;
    if (t < 64) gs[t] = gammaf[b0 + t];
    __syncthreads();
    float betaf = (float)sc[3];
    float s0 = 0.f, s1 = 0.f, s2 = 0.f, s3 = 0.f;
#pragma unroll
    for (int j = 0; j < 64; j += 4) {
        s0 += __expf(gs[j]     - betaf * P[(long)(b0 + j)     * K_N + k]);
        s1 += __expf(gs[j + 1] - betaf * P[(long)(b0 + j + 1) * K_N + k]);
        s2 += __expf(gs[j + 2] - betaf * P[(long)(b0 + j + 2) * K_N + k]);
        s3 += __expf(gs[j + 3] - betaf * P[(long)(b0 + j + 3) * K_N + k]);
    }
    part[(long)blockIdx.y * K_N + k] = (s0 + s1) + (s2 + s3);
}

__global__ __launch_bounds__(256) void k_colsum2(const float* __restrict__ part,
                                                 double* __restrict__ lnr64,
                                                 float* __restrict__ lnrf) {
    int k = blockIdx.x * 256 + threadIdx.x;
    double s = 0.0;
#pragma unroll 4
    for (int c = 0; c < 128; ++c) s += (double)part[(long)c * K_N + k];
    double l = -log(s);
    lnr64[k] = l; lnrf[k] = (float)l;
}

// ---------------- fused rowsum_i + colsum_{i+1}: ONE pass over P ----------------
// 512 blocks x 512 thr; block processes 16 rows. Thread t<511 owns k = 3+4t..3+4t+3
// (16B-aligned float4 on the odd P base); thread 511 owns k = {0,1,2,2047}.
// Per row: block loads row once, reduces gamma_b (f64, fixed order), then
// accumulates colsum partials exp(gamma - beta*P) in registers. Fully deterministic.
__global__ __launch_bounds__(512) void k_fused(const float* __restrict__ P,
                                               const float* __restrict__ lnrf,
                                               const double* __restrict__ sc,
                                               float* __restrict__ part) {
    __shared__ double wred[8];
    int t = threadIdx.x, l = t & 63, w = t >> 6;
    float betaf = (float)sc[3];
    int kbase = 3 + 4 * t;
    float ln0, ln1, ln2, ln3;
    if (t < 511) { ln0 = lnrf[kbase]; ln1 = lnrf[kbase + 1]; ln2 = lnrf[kbase + 2]; ln3 = lnrf[kbase + 3]; }
    else         { ln0 = lnrf[0];     ln1 = lnrf[1];         ln2 = lnrf[2];         ln3 = lnrf[2047]; }
    float4 acc = make_float4(0.f, 0.f, 0.f, 0.f);
    long rowbase = (long)blockIdx.x * 16;
    for (int rr = 0; rr < 16; ++rr) {
        const float* row = P + (rowbase + rr) * K_N;
        float p0, p1, p2, p3;
        if (t < 511) {
            float4 p4 = *(const float4*)(row + kbase);
            p0 = p4.x; p1 = p4.y; p2 = p4.z; p3 = p4.w;
        } else {
            p0 = row[0]; p1 = row[1]; p2 = row[2]; p3 = row[2047];
        }
        float e0 = __expf(ln0 - betaf * p0);
        float e1 = __expf(ln1 - betaf * p1);
        float e2 = __expf(ln2 - betaf * p2);
        float e3 = __expf(ln3 - betaf * p3);
        double s = (double)((e0 + e1) + (e2 + e3));
#pragma unroll
        for (int off = 1; off < 64; off <<= 1) s += __shfl_xor(s, off, 64);
        if (l == 0) wred[w] = s;
        __syncthreads();
        double ss = ((wred[0] + wred[1]) + (wred[2] + wred[3]))
                  + ((wred[4] + wred[5]) + (wred[6] + wred[7]));
        float gf = (float)(-log(ss));
        __syncthreads();
        acc.x += __expf(gf - betaf * p0);
        acc.y += __expf(gf - betaf * p1);
        acc.z += __expf(gf - betaf * p2);
        acc.w += __expf(gf - betaf * p3);
    }
    // slot layout: t<511 -> slots 4t..4t+3 (k=3+4t..); t=511 -> slots 2044..2047 (k=0,1,2,2047)
    ((float4*)(part + (long)blockIdx.x * K_N))[t] = acc;
}

// reduce fused partials -> lnr (wave per k, deterministic)
__global__ __launch_bounds__(512) void k_freduce(const float* __restrict__ part,
                                                 double* __restrict__ lnr64,
                                                 float* __restrict__ lnrf) {
    int t = threadIdx.x, l = t & 63, w = t >> 6;
    int k = blockIdx.x * 8 + w;
    int slot = (k >= 3 && k < 2047) ? (k - 3) : (k < 3 ? 2044 + k : 2047);
    double s = 0.0;
#pragma unroll
    for (int j = 0; j < 8; ++j)
        s += (double)part[(long)(l + 64 * j) * K_N + slot];
#pragma unroll
    for (int off = 1; off < 64; off <<= 1) s += __shfl_xor(s, off, 64);
    if (l == 0) { double v = -log(s); lnr64[k] = v; lnrf[k] = (float)v; }
}

// ---------------- final: wave per row — hoisted loads, argmax(f64), dc in place,
// loss via ||e-x||^2 = A64[b] + P[b,bi] (P recovered from dec), gather emb ----------------
__global__ __launch_bounds__(512) void k_final(const double* __restrict__ lnr64,
                                               const double* __restrict__ sc,
                                               const double* __restrict__ A64,
                                               const float* __restrict__ emb,
                                               float* __restrict__ out,
                                               double* __restrict__ lossp) {
    int t = threadIdx.x, l = t & 63, w = t >> 6;
    long b = (long)blockIdx.x * 8 + w;
    float* row = out + OUT_DC + b * K_N;     // P in, dc out (disjoint per wave)
    double beta = sc[3], mid = sc[0], inva = 1.0 / sc[1];
    double a64b = A64[b];
    // ---- hoist ALL loads before any store (avoid alias serialization) ----
    float pe = 0.f;
    if (l < 3)   pe = row[l];
    if (l == 63) pe = row[2047];
    float4 pv[8];
#pragma unroll
    for (int c = 0; c < 8; ++c) {
        int i = l + 64 * c;
        if (i < 511) pv[c] = *(const float4*)(row + 3 + 4 * i);
    }
    // ---- argmax (in-lane ascending k -> first-max) + dc stores ----
    double best = -1e300; int bi = 1 << 30;
    if (l < 3) {
        double p = (double)pe;
        double dec = lnr64[l] - beta * p;
        if (dec > best) { best = dec; bi = l; }
        row[l] = (float)((a64b + p - mid) * inva);
    }
#pragma unroll
    for (int c = 0; c < 8; ++c) {
        int i = l + 64 * c;
        if (i < 511) {
            int k = 3 + 4 * i;
            double p0 = pv[c].x, p1 = pv[c].y, p2 = pv[c].z, p3 = pv[c].w;
            double d0 = lnr64[k] - beta * p0;
            double d1 = lnr64[k + 1] - beta * p1;
            double d2 = lnr64[k + 2] - beta * p2;
            double d3 = lnr64[k + 3] - beta * p3;
            if (d0 > best) { best = d0; bi = k; }
            if (d1 > best) { best = d1; bi = k + 1; }
            if (d2 > best) { best = d2; bi = k + 2; }
            if (d3 > best) { best = d3; bi = k + 3; }
            float4 dcv;
            dcv.x = (float)((a64b + p0 - mid) * inva);
            dcv.y = (float)((a64b + p1 - mid) * inva);
            dcv.z = (float)((a64b + p2 - mid) * inva);
            dcv.w = (float)((a64b + p3 - mid) * inva);
            *(float4*)(row + k) = dcv;
        }
    }
    if (l == 63) {
        double p = (double)pe;
        double dec = lnr64[2047] - beta * p;
        if (dec > best) { best = dec; bi = 2047; }
        row[2047] = (float)((a64b + p - mid) * inva);
    }
#pragma unroll
    for (int off = 1; off < 64; off <<= 1) {                   // first-max: min idx on ties
        double ov = __shfl_xor(best, off, 64);
        int oi = __shfl_xor(bi, off, 64);
        if (ov > best || (ov == best && oi < bi)) { best = ov; bi = oi; }
    }
    if (l == 0) {
        out[OUT_IDX + b] = (float)bi;
        // ||e_bi - x_b||^2 = A64[b] + P[b,bi]; P recovered: dec = lnr - beta*P
        double prec = (lnr64[bi] - best) / beta;
        lossp[b] = a64b + prec;
    }
    // gather emb -> x_q
    const float4* E4 = (const float4*)(emb + (long)bi * D_N);
    float4* O4 = (float4*)(out + OUT_XQ + b * D_N);
#pragma unroll
    for (int i = 0; i < 3; ++i) O4[i * 64 + l] = E4[i * 64 + l];
}

__global__ __launch_bounds__(1024) void k_loss2(const double* __restrict__ lossp,
                                                float* __restrict__ out) {
    __shared__ double red[1024];
    int t = threadIdx.x;
    double s = 0.0;
#pragma unroll
    for (int j = 0; j < 8; ++j) s += lossp[t + 1024 * j];
    red[t] = s; __syncthreads();
    for (int st = 512; st > 0; st >>= 1) { if (t < st) red[t] += red[t + st]; __syncthreads(); }
    if (t == 0) out[OUT_LOSS] = (float)(red[0] * 1.25 / (double)((long)B_N * D_N));
}

extern "C" void kernel_launch(void* const* d_in, const int* in_sizes, int n_in,
                              void* d_out, int out_size, void* d_ws, size_t ws_size,
                              hipStream_t stream) {
    const float* x  = (const float*)d_in[0];   // [8192,768]
    const float* Am = (const float*)d_in[1];   // [2048,32]
    const float* Bm = (const float*)d_in[2];   // [32,768]
    float* out = (float*)d_out;
    float* P = out + OUT_DC;                   // P lives in dc region; k_final converts in place

    char* ws = (char*)d_ws;
    float*  emb     = (float*)(ws);                 // 6,291,456 B
    // 4 MB pool at +6291456: y (1 MB, dead after pgemm) | cs_part (1 MB, dead after c0's
    // colsum2) | 2 MB spare — reused as fpart [512][2048] f32 by k_fused/k_freduce.
    float*  y       = (float*)(ws + 6291456);       // 1,048,576 B
    float*  cs_part = (float*)(ws + 7340032);       // 128*2048*4 = 1,048,576 B
    float*  fpart   = (float*)(ws + 6291456);       // 512*2048*4 = 4,194,304 B (overlays y+cs_part)
    double* A64     = (double*)(ws + 10485760);     // 65,536 B
    float*  hf      = (float*)(ws + 10551296);      // 8,192 B
    float*  gammaf  = (float*)(ws + 10559488);      // 32,768 B
    double* lnr64   = (double*)(ws + 10592256);     // 16,384 B
    float*  lnrf    = (float*)(ws + 10608640);      // 8,192 B
    double* mmpart  = (double*)(ws + 10616832);     // 2048*2*8 = 32,768 B
    double* sc      = (double*)(ws + 10649600);     // 4 doubles
    double* lossp   = (double*)(ws + 10649856);     // 8192*8 = 65,536 B
    // total ws use ~10.7 MB

    k_emb<<<K_N, 256, 0, stream>>>(Am, Bm, emb, hf);
    k_ygemm<<<B_N / 16, 256, 0, stream>>>(x, Bm, y, A64);

    dim3 gp(K_N / 256, B_N / 32);
    k_pgemm<<<gp, 256, 0, stream>>>(Am, y, hf, A64, P, mmpart);
    k_minmax2<<<1, 256, 0, stream>>>(mmpart, sc, A64, gammaf, 2048);

    // c0 (colsum with gamma0), then 5 fused (rowsum_i + colsum_{i+1}) passes:
    // total colsum x6 / rowsum x5 == R4's schedule; contraction ~0.022/cycle,
    // residual ~2e-10 << ~1e-6 decision gap.
    dim3 ga(K_N / 256, 128);
    k_colsum<<<ga, 256, 0, stream>>>(P, gammaf, sc, cs_part);
    k_colsum2<<<K_N / 256, 256, 0, stream>>>(cs_part, lnr64, lnrf);
    for (int it = 0; it < 5; ++it) {
        k_fused<<<512, 512, 0, stream>>>(P, lnrf, sc, fpart);
        k_freduce<<<256, 512, 0, stream>>>(fpart, lnr64, lnrf);
    }

    k_final<<<B_N / 8, 512, 0, stream>>>(lnr64, sc, A64, emb, out, lossp);
    k_loss2<<<1, 1024, 0, stream>>>(lossp, out);
}